// Round 9
// baseline (442.667 us; speedup 1.0000x reference)
//
#include <hip/hip_runtime.h>
#include <math.h>

#define NROWS 16384
#define DIM   128
#define PROTO 256
#define ROWS_PER_BLK 16
#define MASK_BLOCKS 2048

#define OUT_COLS 256                       // concat(output, repres)
#define LOSS_OFF ((size_t)NROWS * OUT_COLS)      // 4194304
#define MASK_OFF (LOSS_OFF + 1)                  // 4194305

typedef float f32x4 __attribute__((ext_vector_type(4)));
typedef float f32x2 __attribute__((ext_vector_type(2)));

// ws layout (floats): [0,N) top1(int) | [N,2N) d1 | [2N,3N) neg | [3N,4N) flag
//                     | [4N, 4N+DIM*PROTO) memT (transposed memory, [D][P])

// ---------------------------------------------------------------------------
// Kernel 0: memT[d][p] = memory[p][d]  (128 KB, one-time)
// ---------------------------------------------------------------------------
__global__ __launch_bounds__(256) void transpose_mem(
    const float* __restrict__ memory, float* __restrict__ memT)
{
    __shared__ float tile[8][DIM + 1];
    const int t  = threadIdx.x;
    const int p0 = blockIdx.x * 8;
    #pragma unroll
    for (int k = 0; k < 4; ++k) {
        const int idx = t + k * 256;
        const int p = idx >> 7, d = idx & 127;
        tile[p][d] = memory[(size_t)(p0 + p) * DIM + d];
    }
    __syncthreads();
    #pragma unroll
    for (int k = 0; k < 4; ++k) {
        const int idx = t + k * 256;
        const int d = idx >> 3, p = idx & 7;
        memT[(size_t)d * PROTO + p0 + p] = tile[p][d];
    }
}

// ---------------------------------------------------------------------------
// Kernel A: per-16-row block. (unchanged from R8)
// ---------------------------------------------------------------------------
__global__ __launch_bounds__(256) void fused_rows(
    const float* __restrict__ repres,
    const float* __restrict__ memory,
    const float* __restrict__ memT,
    float* __restrict__ out,
    int*   __restrict__ top1w,
    float* __restrict__ d1w,
    float* __restrict__ negw,
    float* __restrict__ flagw)
{
    __shared__ float rep_lds[ROWS_PER_BLK * DIM];    // 8 KB
    __shared__ float s_lds[ROWS_PER_BLK * PROTO];    // 16 KB (scores, then exp)
    __shared__ float inv_lds[ROWS_PER_BLK];

    const int tid  = threadIdx.x;
    const int row0 = blockIdx.x * ROWS_PER_BLK;
    const int rg   = tid >> 6;        // wave -> rows 4rg..4rg+3
    const int lane = tid & 63;        // -> protos 4*lane..4*lane+3 (phase 1)

    // ---- phase 0: stage repres rows into LDS (needed by phases 2/3) ----
    {
        const float4* src = (const float4*)(repres + (size_t)row0 * DIM);
        float4* dst = (float4*)rep_lds;
        dst[tid]       = src[tid];
        dst[tid + 256] = src[tid + 256];
    }
    // no barrier: phase 1 does not read rep_lds

    // ---- phase 1: scores. A: wave-uniform repres rows (scalar path),
    //      B: memT rows, coalesced dwordx4 (lane-consecutive protos). ----
    {
        const int urg = __builtin_amdgcn_readfirstlane(rg);
        const float4* a0 = (const float4*)(repres + (size_t)(row0 + 4 * urg) * DIM);
        const f32x4*  bT = (const f32x4*)memT + lane;          // memT[d][4*lane..]

        float acc[4][4];
        #pragma unroll
        for (int i = 0; i < 4; ++i)
            #pragma unroll
            for (int j = 0; j < 4; ++j) acc[i][j] = 0.f;

        for (int d4 = 0; d4 < DIM / 4; ++d4) {
            float4 a_[4];
            #pragma unroll
            for (int i = 0; i < 4; ++i) a_[i] = a0[i * (DIM / 4) + d4];  // uniform
            f32x4 b_[4];
            #pragma unroll
            for (int k = 0; k < 4; ++k) b_[k] = bT[(4 * d4 + k) * (PROTO / 4)];
            #pragma unroll
            for (int i = 0; i < 4; ++i) {
                #pragma unroll
                for (int j = 0; j < 4; ++j) {
                    acc[i][j] = fmaf(a_[i].x, b_[0][j], acc[i][j]);
                    acc[i][j] = fmaf(a_[i].y, b_[1][j], acc[i][j]);
                    acc[i][j] = fmaf(a_[i].z, b_[2][j], acc[i][j]);
                    acc[i][j] = fmaf(a_[i].w, b_[3][j], acc[i][j]);
                }
            }
        }
        f32x4* s4 = (f32x4*)s_lds;
        #pragma unroll
        for (int i = 0; i < 4; ++i) {
            f32x4 v; v.x = acc[i][0]; v.y = acc[i][1]; v.z = acc[i][2]; v.w = acc[i][3];
            s4[(size_t)(4 * rg + i) * (PROTO / 4) + lane] = v;   // proto 4*lane+j
        }
    }
    __syncthreads();   // covers phase-0 rep staging; s_lds rows are wave-private

    // ---- phase 2: per-wave softmax + top2 + distances (rows 4rg..4rg+3) ----
    {
        for (int q = 0; q < 4; ++q) {
            const int r = rg * 4 + q;
            float s[4]; int pidx[4];
            #pragma unroll
            for (int k = 0; k < 4; ++k) {
                pidx[k] = lane + 64 * k;
                s[k] = s_lds[r * PROTO + pidx[k]];
            }
            float mx = fmaxf(fmaxf(s[0], s[1]), fmaxf(s[2], s[3]));
            #pragma unroll
            for (int off = 1; off < 64; off <<= 1)
                mx = fmaxf(mx, __shfl_xor(mx, off, 64));
            float e[4], sum = 0.f;
            #pragma unroll
            for (int k = 0; k < 4; ++k) { e[k] = __expf(s[k] - mx); sum += e[k]; }
            #pragma unroll
            for (int off = 1; off < 64; off <<= 1)
                sum += __shfl_xor(sum, off, 64);
            #pragma unroll
            for (int k = 0; k < 4; ++k) s_lds[r * PROTO + pidx[k]] = e[k];

            float v1 = s[0], v2 = -INFINITY;
            int   i1 = pidx[0], i2 = 0x7fffffff;
            #pragma unroll
            for (int k = 1; k < 4; ++k) {
                float v = s[k]; int i = pidx[k];
                if (v > v1 || (v == v1 && i < i1)) { v2 = v1; i2 = i1; v1 = v; i1 = i; }
                else if (v > v2 || (v == v2 && i < i2)) { v2 = v; i2 = i; }
            }
            #pragma unroll
            for (int off = 1; off < 64; off <<= 1) {
                float ov1 = __shfl_xor(v1, off, 64), ov2 = __shfl_xor(v2, off, 64);
                int   oi1 = __shfl_xor(i1, off, 64), oi2 = __shfl_xor(i2, off, 64);
                if (ov1 > v1 || (ov1 == v1 && oi1 < i1)) { v2 = v1; i2 = i1; v1 = ov1; i1 = oi1; }
                else if (ov1 > v2 || (ov1 == v2 && oi1 < i2)) { v2 = ov1; i2 = oi1; }
                if (ov2 > v2 || (ov2 == v2 && oi2 < i2)) { v2 = ov2; i2 = oi2; }
            }

            const float rx = rep_lds[r * DIM + 2 * lane];
            const float ry = rep_lds[r * DIM + 2 * lane + 1];
            float dx = rx - memory[(size_t)i1 * DIM + 2 * lane];
            float dy = ry - memory[(size_t)i1 * DIM + 2 * lane + 1];
            float ss1 = dx * dx + dy * dy;
            dx = rx - memory[(size_t)i2 * DIM + 2 * lane];
            dy = ry - memory[(size_t)i2 * DIM + 2 * lane + 1];
            float ss2 = dx * dx + dy * dy;
            #pragma unroll
            for (int off = 1; off < 64; off <<= 1) {
                ss1 += __shfl_xor(ss1, off, 64);
                ss2 += __shfl_xor(ss2, off, 64);
            }
            if (lane == 0) {
                const int grow = row0 + r;
                float dist1 = sqrtf(ss1) / 128.f;
                float dist2 = sqrtf(ss2) / 128.f;
                top1w[grow] = i1;
                d1w[grow]   = dist1;
                float diff  = dist1 - dist2 + 0.001f;
                negw[grow]  = (diff < 0.f) ? diff : 0.f;
                flagw[grow] = (diff < 0.f) ? 1.f : 0.f;
                inv_lds[r]  = 1.0f / sum;
            }
        }
    }
    // no barrier: phase 3 reads only this wave's rows (s_lds, inv_lds, rep_lds)

    // ---- phase 3: out = (e . mem) * inv ; concat repres. 4-row x 2-dim tile ----
    {
        const int d0 = 2 * lane;
        float accx[4], accy[4];
        #pragma unroll
        for (int i = 0; i < 4; ++i) { accx[i] = 0.f; accy[i] = 0.f; }

        const f32x4* s4 = (const f32x4*)s_lds;
        for (int p4 = 0; p4 < PROTO / 4; ++p4) {
            f32x4 e[4];
            #pragma unroll
            for (int i = 0; i < 4; ++i)
                e[i] = s4[(size_t)(4 * rg + i) * (PROTO / 4) + p4];  // wave-uniform bcast
            #pragma unroll
            for (int k = 0; k < 4; ++k) {
                const f32x2 m2 = *(const f32x2*)(memory + (size_t)(p4 * 4 + k) * DIM + d0);
                #pragma unroll
                for (int i = 0; i < 4; ++i) {
                    accx[i] = fmaf(e[i][k], m2.x, accx[i]);
                    accy[i] = fmaf(e[i][k], m2.y, accy[i]);
                }
            }
        }
        #pragma unroll
        for (int i = 0; i < 4; ++i) {
            const int r = 4 * rg + i;
            const size_t grow = (size_t)(row0 + r);
            const float inv = inv_lds[r];
            f32x2 o; o.x = accx[i] * inv; o.y = accy[i] * inv;
            *(f32x2*)(out + grow * OUT_COLS + d0) = o;
            f32x2 rp; rp.x = rep_lds[r * DIM + d0]; rp.y = rep_lds[r * DIM + d0 + 1];
            *(f32x2*)(out + grow * OUT_COLS + 128 + d0) = rp;
        }
    }
}

// ---------------------------------------------------------------------------
// Kernel B: mask as ONE dense grid-stride front (fill-like moving write front,
// ~8 MB wide) + LDS-u8 top1 (zero global loads in hot loop).
// Groups of 4 at m = 3+4g (16B-aligned in out); edges m=0,1,2,NN-1 by block 0.
// Block MASK_BLOCKS: loss reduction.
// ---------------------------------------------------------------------------
__global__ __launch_bounds__(256) void mask_loss_kernel(
    const int* __restrict__ top1,
    const float* __restrict__ memory,
    const float* __restrict__ d1w,
    const float* __restrict__ negw,
    const float* __restrict__ flagw,
    float* __restrict__ out)
{
    const int b   = blockIdx.x;
    const int tid = threadIdx.x;

    if (b == MASK_BLOCKS) {
        __shared__ float red[4 * 256];
        float s1 = 0.f, s2 = 0.f, s3 = 0.f, s4 = 0.f;
        for (int q = tid; q < NROWS; q += 256) {
            s1 += d1w[q]; s2 += negw[q]; s3 += flagw[q];
        }
        for (int q = tid; q < PROTO * DIM; q += 256) {
            float v = memory[q];
            s4 = fmaf(v, v, s4);
        }
        red[tid] = s1; red[256 + tid] = s2; red[512 + tid] = s3; red[768 + tid] = s4;
        __syncthreads();
        for (int off = 128; off > 0; off >>= 1) {
            if (tid < off) {
                red[tid]       += red[tid + off];
                red[256 + tid] += red[256 + tid + off];
                red[512 + tid] += red[512 + tid + off];
                red[768 + tid] += red[768 + tid + off];
            }
            __syncthreads();
        }
        if (tid == 0) {
            float loss = red[0] / (float)NROWS;
            float cnt  = red[512];
            if (cnt > 0.f) loss += red[256] / cnt;
            loss += sqrtf(red[768]);
            out[LOSS_OFF] = loss;
        }
        return;
    }

    // ---- stage top1 as packed u8 into LDS (16 KB): top1[j] < 256 (P=256) ----
    __shared__ unsigned int lds_u32[NROWS / 4];
    unsigned char* lds_u8 = (unsigned char*)lds_u32;
    {
        const int4* t4 = (const int4*)top1;          // 4096 groups
        #pragma unroll
        for (int k = 0; k < 16; ++k) {
            const int g = tid + (k << 8);
            const int4 a = t4[g];
            lds_u32[g] = (unsigned)(a.x & 255) | ((unsigned)(a.y & 255) << 8)
                       | ((unsigned)(a.z & 255) << 16) | ((unsigned)a.w << 24);
        }
    }
    __syncthreads();

    float* __restrict__ mask = out + MASK_OFF;

    // edges: m = 0,1,2 (i=0; j=0,1,2) and m = NN-1 (i=j=N-1)
    if (b == 0) {
        if (tid < 3) {
            mask[tid] = ((int)lds_u8[tid] == (int)lds_u8[0]) ? 1.f : 0.f;
        } else if (tid == 3) {
            mask[(long long)NROWS * NROWS - 1] = 1.f;
        }
    }

    // dense front: group g -> m = 3+4g; lanes consecutive -> 1KB/wave chunks
    const long long NV = (((long long)NROWS * NROWS) - 4) >> 2;   // 67108863
    const long long stride = (long long)MASK_BLOCKS * 256;
    for (long long v = (long long)b * 256 + tid; v < NV; v += stride) {
        const long long m = 3 + (v << 2);
        const int i  = (int)(m >> 14);
        const int j0 = (int)(m & 16383);
        const int w  = j0 >> 2;                       // bytes j0..j0+3 start at byte 3 of word w
        const unsigned w0 = lds_u32[w];
        const unsigned w1 = lds_u32[(w + 1) & 4095];  // wraps at row end (handled below)
        const unsigned x  = (w0 >> 24) | (w1 << 8);   // v_alignbit
        f32x4 val;
        if (j0 != 16383) {                            // fast path: all 4 in row i
            const int ti = (int)lds_u8[i];
            val.x = ((int)( x        & 255) == ti) ? 1.f : 0.f;
            val.y = ((int)((x >> 8 ) & 255) == ti) ? 1.f : 0.f;
            val.z = ((int)((x >> 16) & 255) == ti) ? 1.f : 0.f;
            val.w = ((int)( x >> 24       ) == ti) ? 1.f : 0.f;
        } else {                                      // row-cross: j=16383 (i), j=0,1,2 (i+1)
            const int ti0 = (int)lds_u8[i];
            const int ti1 = (int)lds_u8[i + 1];
            val.x = ((int)( x        & 255) == ti0) ? 1.f : 0.f;
            val.y = ((int)((x >> 8 ) & 255) == ti1) ? 1.f : 0.f;
            val.z = ((int)((x >> 16) & 255) == ti1) ? 1.f : 0.f;
            val.w = ((int)( x >> 24       ) == ti1) ? 1.f : 0.f;
        }
        *(f32x4*)(mask + m) = val;
    }
}

// ---------------------------------------------------------------------------
extern "C" void kernel_launch(void* const* d_in, const int* in_sizes, int n_in,
                              void* d_out, int out_size, void* d_ws, size_t ws_size,
                              hipStream_t stream)
{
    const float* repres = (const float*)d_in[0];
    const float* memory = (const float*)d_in[1];
    float* out = (float*)d_out;

    int*   top1w = (int*)d_ws;                 // ws: 256 KB arrays + 128 KB memT
    float* fws   = (float*)d_ws;
    float* d1w   = fws + NROWS;
    float* negw  = fws + 2 * NROWS;
    float* flagw = fws + 3 * NROWS;
    float* memTw = fws + 4 * NROWS;

    transpose_mem<<<dim3(PROTO / 8), dim3(256), 0, stream>>>(memory, memTw);
    fused_rows<<<dim3(NROWS / ROWS_PER_BLK), dim3(256), 0, stream>>>(
        repres, memory, memTw, out, top1w, d1w, negw, flagw);
    mask_loss_kernel<<<dim3(MASK_BLOCKS + 1), dim3(256), 0, stream>>>(
        top1w, memory, d1w, negw, flagw, out);
}

// Round 10
// 301.383 us; speedup vs baseline: 1.4688x; 1.4688x over previous
//
#include <hip/hip_runtime.h>
#include <math.h>

#define NROWS 16384
#define DIM   128
#define PROTO 256
#define ROWS_PER_BLK 16
#define MASK_ROWS_PER_BLK 64
#define MASK_BLOCKS (NROWS / MASK_ROWS_PER_BLK)   // 256

#define OUT_COLS 256                       // concat(output, repres)
#define LOSS_OFF ((size_t)NROWS * OUT_COLS)      // 4194304
#define MASK_OFF (LOSS_OFF + 1)                  // 4194305

typedef float f32x4 __attribute__((ext_vector_type(4)));
typedef float f32x2 __attribute__((ext_vector_type(2)));

// ws layout (floats): [0,N) top1(int) | [N,2N) d1 | [2N,3N) neg | [3N,4N) flag
//                     | [4N, 4N+DIM*PROTO) memT (transposed memory, [D][P])

// ---------------------------------------------------------------------------
// Kernel 0: memT[d][p] = memory[p][d]  (128 KB, one-time)
// ---------------------------------------------------------------------------
__global__ __launch_bounds__(256) void transpose_mem(
    const float* __restrict__ memory, float* __restrict__ memT)
{
    __shared__ float tile[8][DIM + 1];
    const int t  = threadIdx.x;
    const int p0 = blockIdx.x * 8;
    #pragma unroll
    for (int k = 0; k < 4; ++k) {
        const int idx = t + k * 256;
        const int p = idx >> 7, d = idx & 127;
        tile[p][d] = memory[(size_t)(p0 + p) * DIM + d];
    }
    __syncthreads();
    #pragma unroll
    for (int k = 0; k < 4; ++k) {
        const int idx = t + k * 256;
        const int d = idx >> 3, p = idx & 7;
        memT[(size_t)d * PROTO + p0 + p] = tile[p][d];
    }
}

// ---------------------------------------------------------------------------
// Kernel A: per-16-row block. (unchanged from R8)
// ---------------------------------------------------------------------------
__global__ __launch_bounds__(256) void fused_rows(
    const float* __restrict__ repres,
    const float* __restrict__ memory,
    const float* __restrict__ memT,
    float* __restrict__ out,
    int*   __restrict__ top1w,
    float* __restrict__ d1w,
    float* __restrict__ negw,
    float* __restrict__ flagw)
{
    __shared__ float rep_lds[ROWS_PER_BLK * DIM];    // 8 KB
    __shared__ float s_lds[ROWS_PER_BLK * PROTO];    // 16 KB (scores, then exp)
    __shared__ float inv_lds[ROWS_PER_BLK];

    const int tid  = threadIdx.x;
    const int row0 = blockIdx.x * ROWS_PER_BLK;
    const int rg   = tid >> 6;        // wave -> rows 4rg..4rg+3
    const int lane = tid & 63;        // -> protos 4*lane..4*lane+3 (phase 1)

    // ---- phase 0: stage repres rows into LDS (needed by phases 2/3) ----
    {
        const float4* src = (const float4*)(repres + (size_t)row0 * DIM);
        float4* dst = (float4*)rep_lds;
        dst[tid]       = src[tid];
        dst[tid + 256] = src[tid + 256];
    }
    // no barrier: phase 1 does not read rep_lds

    // ---- phase 1: scores. A: wave-uniform repres rows (scalar path),
    //      B: memT rows, coalesced dwordx4 (lane-consecutive protos). ----
    {
        const int urg = __builtin_amdgcn_readfirstlane(rg);
        const float4* a0 = (const float4*)(repres + (size_t)(row0 + 4 * urg) * DIM);
        const f32x4*  bT = (const f32x4*)memT + lane;          // memT[d][4*lane..]

        float acc[4][4];
        #pragma unroll
        for (int i = 0; i < 4; ++i)
            #pragma unroll
            for (int j = 0; j < 4; ++j) acc[i][j] = 0.f;

        for (int d4 = 0; d4 < DIM / 4; ++d4) {
            float4 a_[4];
            #pragma unroll
            for (int i = 0; i < 4; ++i) a_[i] = a0[i * (DIM / 4) + d4];  // uniform
            f32x4 b_[4];
            #pragma unroll
            for (int k = 0; k < 4; ++k) b_[k] = bT[(4 * d4 + k) * (PROTO / 4)];
            #pragma unroll
            for (int i = 0; i < 4; ++i) {
                #pragma unroll
                for (int j = 0; j < 4; ++j) {
                    acc[i][j] = fmaf(a_[i].x, b_[0][j], acc[i][j]);
                    acc[i][j] = fmaf(a_[i].y, b_[1][j], acc[i][j]);
                    acc[i][j] = fmaf(a_[i].z, b_[2][j], acc[i][j]);
                    acc[i][j] = fmaf(a_[i].w, b_[3][j], acc[i][j]);
                }
            }
        }
        f32x4* s4 = (f32x4*)s_lds;
        #pragma unroll
        for (int i = 0; i < 4; ++i) {
            f32x4 v; v.x = acc[i][0]; v.y = acc[i][1]; v.z = acc[i][2]; v.w = acc[i][3];
            s4[(size_t)(4 * rg + i) * (PROTO / 4) + lane] = v;   // proto 4*lane+j
        }
    }
    __syncthreads();   // covers phase-0 rep staging; s_lds rows are wave-private

    // ---- phase 2: per-wave softmax + top2 + distances (rows 4rg..4rg+3) ----
    {
        for (int q = 0; q < 4; ++q) {
            const int r = rg * 4 + q;
            float s[4]; int pidx[4];
            #pragma unroll
            for (int k = 0; k < 4; ++k) {
                pidx[k] = lane + 64 * k;
                s[k] = s_lds[r * PROTO + pidx[k]];
            }
            float mx = fmaxf(fmaxf(s[0], s[1]), fmaxf(s[2], s[3]));
            #pragma unroll
            for (int off = 1; off < 64; off <<= 1)
                mx = fmaxf(mx, __shfl_xor(mx, off, 64));
            float e[4], sum = 0.f;
            #pragma unroll
            for (int k = 0; k < 4; ++k) { e[k] = __expf(s[k] - mx); sum += e[k]; }
            #pragma unroll
            for (int off = 1; off < 64; off <<= 1)
                sum += __shfl_xor(sum, off, 64);
            #pragma unroll
            for (int k = 0; k < 4; ++k) s_lds[r * PROTO + pidx[k]] = e[k];

            float v1 = s[0], v2 = -INFINITY;
            int   i1 = pidx[0], i2 = 0x7fffffff;
            #pragma unroll
            for (int k = 1; k < 4; ++k) {
                float v = s[k]; int i = pidx[k];
                if (v > v1 || (v == v1 && i < i1)) { v2 = v1; i2 = i1; v1 = v; i1 = i; }
                else if (v > v2 || (v == v2 && i < i2)) { v2 = v; i2 = i; }
            }
            #pragma unroll
            for (int off = 1; off < 64; off <<= 1) {
                float ov1 = __shfl_xor(v1, off, 64), ov2 = __shfl_xor(v2, off, 64);
                int   oi1 = __shfl_xor(i1, off, 64), oi2 = __shfl_xor(i2, off, 64);
                if (ov1 > v1 || (ov1 == v1 && oi1 < i1)) { v2 = v1; i2 = i1; v1 = ov1; i1 = oi1; }
                else if (ov1 > v2 || (ov1 == v2 && oi1 < i2)) { v2 = ov1; i2 = oi1; }
                if (ov2 > v2 || (ov2 == v2 && oi2 < i2)) { v2 = ov2; i2 = oi2; }
            }

            const float rx = rep_lds[r * DIM + 2 * lane];
            const float ry = rep_lds[r * DIM + 2 * lane + 1];
            float dx = rx - memory[(size_t)i1 * DIM + 2 * lane];
            float dy = ry - memory[(size_t)i1 * DIM + 2 * lane + 1];
            float ss1 = dx * dx + dy * dy;
            dx = rx - memory[(size_t)i2 * DIM + 2 * lane];
            dy = ry - memory[(size_t)i2 * DIM + 2 * lane + 1];
            float ss2 = dx * dx + dy * dy;
            #pragma unroll
            for (int off = 1; off < 64; off <<= 1) {
                ss1 += __shfl_xor(ss1, off, 64);
                ss2 += __shfl_xor(ss2, off, 64);
            }
            if (lane == 0) {
                const int grow = row0 + r;
                float dist1 = sqrtf(ss1) / 128.f;
                float dist2 = sqrtf(ss2) / 128.f;
                top1w[grow] = i1;
                d1w[grow]   = dist1;
                float diff  = dist1 - dist2 + 0.001f;
                negw[grow]  = (diff < 0.f) ? diff : 0.f;
                flagw[grow] = (diff < 0.f) ? 1.f : 0.f;
                inv_lds[r]  = 1.0f / sum;
            }
        }
    }
    // no barrier: phase 3 reads only this wave's rows (s_lds, inv_lds, rep_lds)

    // ---- phase 3: out = (e . mem) * inv ; concat repres. 4-row x 2-dim tile ----
    {
        const int d0 = 2 * lane;
        float accx[4], accy[4];
        #pragma unroll
        for (int i = 0; i < 4; ++i) { accx[i] = 0.f; accy[i] = 0.f; }

        const f32x4* s4 = (const f32x4*)s_lds;
        for (int p4 = 0; p4 < PROTO / 4; ++p4) {
            f32x4 e[4];
            #pragma unroll
            for (int i = 0; i < 4; ++i)
                e[i] = s4[(size_t)(4 * rg + i) * (PROTO / 4) + p4];  // wave-uniform bcast
            #pragma unroll
            for (int k = 0; k < 4; ++k) {
                const f32x2 m2 = *(const f32x2*)(memory + (size_t)(p4 * 4 + k) * DIM + d0);
                #pragma unroll
                for (int i = 0; i < 4; ++i) {
                    accx[i] = fmaf(e[i][k], m2.x, accx[i]);
                    accy[i] = fmaf(e[i][k], m2.y, accy[i]);
                }
            }
        }
        #pragma unroll
        for (int i = 0; i < 4; ++i) {
            const int r = 4 * rg + i;
            const size_t grow = (size_t)(row0 + r);
            const float inv = inv_lds[r];
            f32x2 o; o.x = accx[i] * inv; o.y = accy[i] * inv;
            *(f32x2*)(out + grow * OUT_COLS + d0) = o;
            f32x2 rp; rp.x = rep_lds[r * DIM + d0]; rp.y = rep_lds[r * DIM + d0 + 1];
            *(f32x2*)(out + grow * OUT_COLS + 128 + d0) = rp;
        }
    }
}

// ---------------------------------------------------------------------------
// Kernel B: mask via LDS-staged u8 top1, block-per-64-rows (256 blocks =
// 1 block/CU, ~4 waves/CU — mimics the 6.5 TB/s fill kernel's occupancy;
// 256 concurrent 4MB write streams instead of 2048x512KB).
// Stores 128B-line-aligned (body starts at j=31). Block MASK_BLOCKS: loss.
// ---------------------------------------------------------------------------
__global__ __launch_bounds__(256) void mask_loss_kernel(
    const int* __restrict__ top1,
    const float* __restrict__ memory,
    const float* __restrict__ d1w,
    const float* __restrict__ negw,
    const float* __restrict__ flagw,
    float* __restrict__ out)
{
    const int b   = blockIdx.x;
    const int tid = threadIdx.x;

    if (b == MASK_BLOCKS) {
        __shared__ float red[4 * 256];
        float s1 = 0.f, s2 = 0.f, s3 = 0.f, s4 = 0.f;
        for (int q = tid; q < NROWS; q += 256) {
            s1 += d1w[q]; s2 += negw[q]; s3 += flagw[q];
        }
        for (int q = tid; q < PROTO * DIM; q += 256) {
            float v = memory[q];
            s4 = fmaf(v, v, s4);
        }
        red[tid] = s1; red[256 + tid] = s2; red[512 + tid] = s3; red[768 + tid] = s4;
        __syncthreads();
        for (int off = 128; off > 0; off >>= 1) {
            if (tid < off) {
                red[tid]       += red[tid + off];
                red[256 + tid] += red[256 + tid + off];
                red[512 + tid] += red[512 + tid + off];
                red[768 + tid] += red[768 + tid + off];
            }
            __syncthreads();
        }
        if (tid == 0) {
            float loss = red[0] / (float)NROWS;
            float cnt  = red[512];
            if (cnt > 0.f) loss += red[256] / cnt;
            loss += sqrtf(red[768]);
            out[LOSS_OFF] = loss;
        }
        return;
    }

    // ---- stage top1 as packed u8 into LDS (16 KB): top1[j] < 256 (P=256) ----
    __shared__ unsigned int lds_u32[NROWS / 4];
    unsigned char* lds_u8 = (unsigned char*)lds_u32;
    {
        const int4* t4 = (const int4*)top1;          // 4096 groups
        #pragma unroll
        for (int k = 0; k < 16; ++k) {
            const int g = tid + (k << 8);
            const int4 a = t4[g];
            lds_u32[g] = (unsigned)(a.x & 255) | ((unsigned)(a.y & 255) << 8)
                       | ((unsigned)(a.z & 255) << 16) | ((unsigned)a.w << 24);
        }
    }
    __syncthreads();

    // ---- 64 rows per block; hot loop: ds_read + byte unpack + aligned store ----
    for (int rr = 0; rr < MASK_ROWS_PER_BLK; ++rr) {
        const int r = b * MASK_ROWS_PER_BLK + rr;
        const int ti = (int)lds_u8[r];               // wave-uniform broadcast
        float* __restrict__ row = out + MASK_OFF + (size_t)r * NROWS;

        // head j in [0,31) and tail j = NROWS-1
        if (tid < 31) {
            row[tid] = ((int)lds_u8[tid] == ti) ? 1.f : 0.f;
        } else if (tid == 31) {
            row[NROWS - 1] = ((int)lds_u8[NROWS - 1] == ti) ? 1.f : 0.f;
        }

        // body: 4088 groups of 4, j0 = 31 + 4h; 128B-aligned 1KB wave spans
        #pragma unroll 4
        for (int k = 0; k < 16; ++k) {
            const int h = tid + (k << 8);
            if (h < 4088) {
                const unsigned w0 = lds_u32[h + 7];   // bytes 4h+28..31 (j0 = byte3)
                const unsigned w1 = lds_u32[h + 8];   // bytes j0+1..j0+4
                const unsigned x  = (w0 >> 24) | (w1 << 8);   // v_alignbit
                f32x4 v;
                v.x = ((int)(x & 255)         == ti) ? 1.f : 0.f;
                v.y = ((int)((x >> 8) & 255)  == ti) ? 1.f : 0.f;
                v.z = ((int)((x >> 16) & 255) == ti) ? 1.f : 0.f;
                v.w = ((int)(x >> 24)         == ti) ? 1.f : 0.f;
                *(f32x4*)(row + 31 + (h << 2)) = v;
            }
        }
    }
}

// ---------------------------------------------------------------------------
extern "C" void kernel_launch(void* const* d_in, const int* in_sizes, int n_in,
                              void* d_out, int out_size, void* d_ws, size_t ws_size,
                              hipStream_t stream)
{
    const float* repres = (const float*)d_in[0];
    const float* memory = (const float*)d_in[1];
    float* out = (float*)d_out;

    int*   top1w = (int*)d_ws;                 // ws: 256 KB arrays + 128 KB memT
    float* fws   = (float*)d_ws;
    float* d1w   = fws + NROWS;
    float* negw  = fws + 2 * NROWS;
    float* flagw = fws + 3 * NROWS;
    float* memTw = fws + 4 * NROWS;

    transpose_mem<<<dim3(PROTO / 8), dim3(256), 0, stream>>>(memory, memTw);
    fused_rows<<<dim3(NROWS / ROWS_PER_BLK), dim3(256), 0, stream>>>(
        repres, memory, memTw, out, top1w, d1w, negw, flagw);
    mask_loss_kernel<<<dim3(MASK_BLOCKS + 1), dim3(256), 0, stream>>>(
        top1w, memory, d1w, negw, flagw, out);
}

// Round 11
// 259.146 us; speedup vs baseline: 1.7082x; 1.1630x over previous
//
#include <hip/hip_runtime.h>
#include <math.h>

#define NROWS 16384
#define DIM   128
#define PROTO 256
#define ROWS_PER_BLK 16
#define MASK_ROWS_PER_BLK 64
#define MASK_BLOCKS (NROWS / MASK_ROWS_PER_BLK)   // 256
#define OUT_BLOCKS  (NROWS / ROWS_PER_BLK)        // 1024

#define OUT_COLS 256                       // concat(output, repres)
#define LOSS_OFF ((size_t)NROWS * OUT_COLS)      // 4194304
#define MASK_OFF (LOSS_OFF + 1)                  // 4194305

typedef float f32x4 __attribute__((ext_vector_type(4)));
typedef float f32x2 __attribute__((ext_vector_type(2)));

// ws layout (floats): [0,N) top1(int) | [N,2N) d1 | [2N,3N) neg | [3N,4N) flag
//                     | [4N, 4N+DIM*PROTO) memT (transposed memory, [D][P])

// ---------------------------------------------------------------------------
// Kernel 0: memT[d][p] = memory[p][d]  (128 KB, one-time)
// ---------------------------------------------------------------------------
__global__ __launch_bounds__(256) void transpose_mem(
    const float* __restrict__ memory, float* __restrict__ memT)
{
    __shared__ float tile[8][DIM + 1];
    const int t  = threadIdx.x;
    const int p0 = blockIdx.x * 8;
    #pragma unroll
    for (int k = 0; k < 4; ++k) {
        const int idx = t + k * 256;
        const int p = idx >> 7, d = idx & 127;
        tile[p][d] = memory[(size_t)(p0 + p) * DIM + d];
    }
    __syncthreads();
    #pragma unroll
    for (int k = 0; k < 4; ++k) {
        const int idx = t + k * 256;
        const int d = idx >> 3, p = idx & 7;
        memT[(size_t)d * PROTO + p0 + p] = tile[p][d];
    }
}

// ---------------------------------------------------------------------------
// Kernel 1: top-only — scores GEMM -> top2 -> distances -> top1/d1/neg/flag.
// (R10 fused phases 0-2 minus softmax; no output GEMM.)
// ---------------------------------------------------------------------------
__global__ __launch_bounds__(256) void top_kernel(
    const float* __restrict__ repres,
    const float* __restrict__ memory,
    const float* __restrict__ memT,
    int*   __restrict__ top1w,
    float* __restrict__ d1w,
    float* __restrict__ negw,
    float* __restrict__ flagw)
{
    __shared__ float rep_lds[ROWS_PER_BLK * DIM];    // 8 KB
    __shared__ float s_lds[ROWS_PER_BLK * PROTO];    // 16 KB

    const int tid  = threadIdx.x;
    const int row0 = blockIdx.x * ROWS_PER_BLK;
    const int rg   = tid >> 6;
    const int lane = tid & 63;

    // phase 0: stage repres (for distances)
    {
        const float4* src = (const float4*)(repres + (size_t)row0 * DIM);
        float4* dst = (float4*)rep_lds;
        dst[tid]       = src[tid];
        dst[tid + 256] = src[tid + 256];
    }

    // phase 1: scores (uniform A via scalar path, coalesced B via memT)
    {
        const int urg = __builtin_amdgcn_readfirstlane(rg);
        const float4* a0 = (const float4*)(repres + (size_t)(row0 + 4 * urg) * DIM);
        const f32x4*  bT = (const f32x4*)memT + lane;

        float acc[4][4];
        #pragma unroll
        for (int i = 0; i < 4; ++i)
            #pragma unroll
            for (int j = 0; j < 4; ++j) acc[i][j] = 0.f;

        for (int d4 = 0; d4 < DIM / 4; ++d4) {
            float4 a_[4];
            #pragma unroll
            for (int i = 0; i < 4; ++i) a_[i] = a0[i * (DIM / 4) + d4];
            f32x4 b_[4];
            #pragma unroll
            for (int k = 0; k < 4; ++k) b_[k] = bT[(4 * d4 + k) * (PROTO / 4)];
            #pragma unroll
            for (int i = 0; i < 4; ++i) {
                #pragma unroll
                for (int j = 0; j < 4; ++j) {
                    acc[i][j] = fmaf(a_[i].x, b_[0][j], acc[i][j]);
                    acc[i][j] = fmaf(a_[i].y, b_[1][j], acc[i][j]);
                    acc[i][j] = fmaf(a_[i].z, b_[2][j], acc[i][j]);
                    acc[i][j] = fmaf(a_[i].w, b_[3][j], acc[i][j]);
                }
            }
        }
        f32x4* s4 = (f32x4*)s_lds;
        #pragma unroll
        for (int i = 0; i < 4; ++i) {
            f32x4 v; v.x = acc[i][0]; v.y = acc[i][1]; v.z = acc[i][2]; v.w = acc[i][3];
            s4[(size_t)(4 * rg + i) * (PROTO / 4) + lane] = v;
        }
    }
    __syncthreads();

    // phase 2-lite: top2 + distances per wave-owned rows
    for (int q = 0; q < 4; ++q) {
        const int r = rg * 4 + q;
        float s[4]; int pidx[4];
        #pragma unroll
        for (int k = 0; k < 4; ++k) {
            pidx[k] = lane + 64 * k;
            s[k] = s_lds[r * PROTO + pidx[k]];
        }
        float v1 = s[0], v2 = -INFINITY;
        int   i1 = pidx[0], i2 = 0x7fffffff;
        #pragma unroll
        for (int k = 1; k < 4; ++k) {
            float v = s[k]; int i = pidx[k];
            if (v > v1 || (v == v1 && i < i1)) { v2 = v1; i2 = i1; v1 = v; i1 = i; }
            else if (v > v2 || (v == v2 && i < i2)) { v2 = v; i2 = i; }
        }
        #pragma unroll
        for (int off = 1; off < 64; off <<= 1) {
            float ov1 = __shfl_xor(v1, off, 64), ov2 = __shfl_xor(v2, off, 64);
            int   oi1 = __shfl_xor(i1, off, 64), oi2 = __shfl_xor(i2, off, 64);
            if (ov1 > v1 || (ov1 == v1 && oi1 < i1)) { v2 = v1; i2 = i1; v1 = ov1; i1 = oi1; }
            else if (ov1 > v2 || (ov1 == v2 && oi1 < i2)) { v2 = ov1; i2 = oi1; }
            if (ov2 > v2 || (ov2 == v2 && oi2 < i2)) { v2 = ov2; i2 = oi2; }
        }

        const float rx = rep_lds[r * DIM + 2 * lane];
        const float ry = rep_lds[r * DIM + 2 * lane + 1];
        float dx = rx - memory[(size_t)i1 * DIM + 2 * lane];
        float dy = ry - memory[(size_t)i1 * DIM + 2 * lane + 1];
        float ss1 = dx * dx + dy * dy;
        dx = rx - memory[(size_t)i2 * DIM + 2 * lane];
        dy = ry - memory[(size_t)i2 * DIM + 2 * lane + 1];
        float ss2 = dx * dx + dy * dy;
        #pragma unroll
        for (int off = 1; off < 64; off <<= 1) {
            ss1 += __shfl_xor(ss1, off, 64);
            ss2 += __shfl_xor(ss2, off, 64);
        }
        if (lane == 0) {
            const int grow = row0 + r;
            float dist1 = sqrtf(ss1) / 128.f;
            float dist2 = sqrtf(ss2) / 128.f;
            top1w[grow] = i1;
            d1w[grow]   = dist1;
            float diff  = dist1 - dist2 + 0.001f;
            negw[grow]  = (diff < 0.f) ? diff : 0.f;
            flagw[grow] = (diff < 0.f) ? 1.f : 0.f;
        }
    }
}

// ---------------------------------------------------------------------------
// Kernel 2: role-split combo.
//   b in [0,256):   mask rows 64b..64b+63 (R10 verbatim; LDS-u8 top1,
//                   line-aligned stores, 1 block/CU-scale stream count)
//   b == 256:       loss reduction
//   b in (256,1281): output GEMM: softmax + e.mem*inv + repres concat,
//                   rows 16*(b-257).. (hides under the mask store stream)
// ---------------------------------------------------------------------------
__global__ __launch_bounds__(256) void combo_kernel(
    const float* __restrict__ repres,
    const float* __restrict__ memory,
    const float* __restrict__ memT,
    const int* __restrict__ top1,
    const float* __restrict__ d1w,
    const float* __restrict__ negw,
    const float* __restrict__ flagw,
    float* __restrict__ out)
{
    const int b   = blockIdx.x;
    const int tid = threadIdx.x;

    if (b < MASK_BLOCKS) {
        // ---- mask: stage top1 as packed u8 (16 KB) ----
        __shared__ unsigned int lds_u32[NROWS / 4];
        unsigned char* lds_u8 = (unsigned char*)lds_u32;
        {
            const int4* t4 = (const int4*)top1;
            #pragma unroll
            for (int k = 0; k < 16; ++k) {
                const int g = tid + (k << 8);
                const int4 a = t4[g];
                lds_u32[g] = (unsigned)(a.x & 255) | ((unsigned)(a.y & 255) << 8)
                           | ((unsigned)(a.z & 255) << 16) | ((unsigned)a.w << 24);
            }
        }
        __syncthreads();

        for (int rr = 0; rr < MASK_ROWS_PER_BLK; ++rr) {
            const int r = b * MASK_ROWS_PER_BLK + rr;
            const int ti = (int)lds_u8[r];
            float* __restrict__ row = out + MASK_OFF + (size_t)r * NROWS;

            if (tid < 31) {
                row[tid] = ((int)lds_u8[tid] == ti) ? 1.f : 0.f;
            } else if (tid == 31) {
                row[NROWS - 1] = ((int)lds_u8[NROWS - 1] == ti) ? 1.f : 0.f;
            }

            #pragma unroll 4
            for (int k = 0; k < 16; ++k) {
                const int h = tid + (k << 8);
                if (h < 4088) {
                    const unsigned w0 = lds_u32[h + 7];
                    const unsigned w1 = lds_u32[h + 8];
                    const unsigned x  = (w0 >> 24) | (w1 << 8);
                    f32x4 v;
                    v.x = ((int)(x & 255)         == ti) ? 1.f : 0.f;
                    v.y = ((int)((x >> 8) & 255)  == ti) ? 1.f : 0.f;
                    v.z = ((int)((x >> 16) & 255) == ti) ? 1.f : 0.f;
                    v.w = ((int)(x >> 24)         == ti) ? 1.f : 0.f;
                    *(f32x4*)(row + 31 + (h << 2)) = v;
                }
            }
        }
        return;
    }

    if (b == MASK_BLOCKS) {
        // ---- loss reduction ----
        __shared__ float red[4 * 256];
        float s1 = 0.f, s2 = 0.f, s3 = 0.f, s4 = 0.f;
        for (int q = tid; q < NROWS; q += 256) {
            s1 += d1w[q]; s2 += negw[q]; s3 += flagw[q];
        }
        for (int q = tid; q < PROTO * DIM; q += 256) {
            float v = memory[q];
            s4 = fmaf(v, v, s4);
        }
        red[tid] = s1; red[256 + tid] = s2; red[512 + tid] = s3; red[768 + tid] = s4;
        __syncthreads();
        for (int off = 128; off > 0; off >>= 1) {
            if (tid < off) {
                red[tid]       += red[tid + off];
                red[256 + tid] += red[256 + tid + off];
                red[512 + tid] += red[512 + tid + off];
                red[768 + tid] += red[768 + tid + off];
            }
            __syncthreads();
        }
        if (tid == 0) {
            float loss = red[0] / (float)NROWS;
            float cnt  = red[512];
            if (cnt > 0.f) loss += red[256] / cnt;
            loss += sqrtf(red[768]);
            out[LOSS_OFF] = loss;
        }
        return;
    }

    // ---- output GEMM block: rows 16*(b-257) .. +15 ----
    __shared__ float rep_lds[ROWS_PER_BLK * DIM];
    __shared__ float s_lds[ROWS_PER_BLK * PROTO];
    __shared__ float inv_lds[ROWS_PER_BLK];

    const int row0 = (b - MASK_BLOCKS - 1) * ROWS_PER_BLK;
    const int rg   = tid >> 6;
    const int lane = tid & 63;

    {
        const float4* src = (const float4*)(repres + (size_t)row0 * DIM);
        float4* dst = (float4*)rep_lds;
        dst[tid]       = src[tid];
        dst[tid + 256] = src[tid + 256];
    }

    {
        const int urg = __builtin_amdgcn_readfirstlane(rg);
        const float4* a0 = (const float4*)(repres + (size_t)(row0 + 4 * urg) * DIM);
        const f32x4*  bT = (const f32x4*)memT + lane;

        float acc[4][4];
        #pragma unroll
        for (int i = 0; i < 4; ++i)
            #pragma unroll
            for (int j = 0; j < 4; ++j) acc[i][j] = 0.f;

        for (int d4 = 0; d4 < DIM / 4; ++d4) {
            float4 a_[4];
            #pragma unroll
            for (int i = 0; i < 4; ++i) a_[i] = a0[i * (DIM / 4) + d4];
            f32x4 b_[4];
            #pragma unroll
            for (int k = 0; k < 4; ++k) b_[k] = bT[(4 * d4 + k) * (PROTO / 4)];
            #pragma unroll
            for (int i = 0; i < 4; ++i) {
                #pragma unroll
                for (int j = 0; j < 4; ++j) {
                    acc[i][j] = fmaf(a_[i].x, b_[0][j], acc[i][j]);
                    acc[i][j] = fmaf(a_[i].y, b_[1][j], acc[i][j]);
                    acc[i][j] = fmaf(a_[i].z, b_[2][j], acc[i][j]);
                    acc[i][j] = fmaf(a_[i].w, b_[3][j], acc[i][j]);
                }
            }
        }
        f32x4* s4 = (f32x4*)s_lds;
        #pragma unroll
        for (int i = 0; i < 4; ++i) {
            f32x4 v; v.x = acc[i][0]; v.y = acc[i][1]; v.z = acc[i][2]; v.w = acc[i][3];
            s4[(size_t)(4 * rg + i) * (PROTO / 4) + lane] = v;
        }
    }
    __syncthreads();

    // softmax (mx, exp, sum) per wave-owned rows; write e back to s_lds
    for (int q = 0; q < 4; ++q) {
        const int r = rg * 4 + q;
        float s[4]; int pidx[4];
        #pragma unroll
        for (int k = 0; k < 4; ++k) {
            pidx[k] = lane + 64 * k;
            s[k] = s_lds[r * PROTO + pidx[k]];
        }
        float mx = fmaxf(fmaxf(s[0], s[1]), fmaxf(s[2], s[3]));
        #pragma unroll
        for (int off = 1; off < 64; off <<= 1)
            mx = fmaxf(mx, __shfl_xor(mx, off, 64));
        float e[4], sum = 0.f;
        #pragma unroll
        for (int k = 0; k < 4; ++k) { e[k] = __expf(s[k] - mx); sum += e[k]; }
        #pragma unroll
        for (int off = 1; off < 64; off <<= 1)
            sum += __shfl_xor(sum, off, 64);
        #pragma unroll
        for (int k = 0; k < 4; ++k) s_lds[r * PROTO + pidx[k]] = e[k];
        if (lane == 0) inv_lds[r] = 1.0f / sum;
    }
    // no barrier: phase 3 reads only this wave's rows

    {
        const int d0 = 2 * lane;
        float accx[4], accy[4];
        #pragma unroll
        for (int i = 0; i < 4; ++i) { accx[i] = 0.f; accy[i] = 0.f; }

        const f32x4* s4 = (const f32x4*)s_lds;
        for (int p4 = 0; p4 < PROTO / 4; ++p4) {
            f32x4 e[4];
            #pragma unroll
            for (int i = 0; i < 4; ++i)
                e[i] = s4[(size_t)(4 * rg + i) * (PROTO / 4) + p4];
            #pragma unroll
            for (int k = 0; k < 4; ++k) {
                const f32x2 m2 = *(const f32x2*)(memory + (size_t)(p4 * 4 + k) * DIM + d0);
                #pragma unroll
                for (int i = 0; i < 4; ++i) {
                    accx[i] = fmaf(e[i][k], m2.x, accx[i]);
                    accy[i] = fmaf(e[i][k], m2.y, accy[i]);
                }
            }
        }
        #pragma unroll
        for (int i = 0; i < 4; ++i) {
            const int r = 4 * rg + i;
            const size_t grow = (size_t)(row0 + r);
            const float inv = inv_lds[r];
            f32x2 o; o.x = accx[i] * inv; o.y = accy[i] * inv;
            *(f32x2*)(out + grow * OUT_COLS + d0) = o;
            f32x2 rp; rp.x = rep_lds[r * DIM + d0]; rp.y = rep_lds[r * DIM + d0 + 1];
            *(f32x2*)(out + grow * OUT_COLS + 128 + d0) = rp;
        }
    }
}

// ---------------------------------------------------------------------------
extern "C" void kernel_launch(void* const* d_in, const int* in_sizes, int n_in,
                              void* d_out, int out_size, void* d_ws, size_t ws_size,
                              hipStream_t stream)
{
    const float* repres = (const float*)d_in[0];
    const float* memory = (const float*)d_in[1];
    float* out = (float*)d_out;

    int*   top1w = (int*)d_ws;                 // ws: 256 KB arrays + 128 KB memT
    float* fws   = (float*)d_ws;
    float* d1w   = fws + NROWS;
    float* negw  = fws + 2 * NROWS;
    float* flagw = fws + 3 * NROWS;
    float* memTw = fws + 4 * NROWS;

    transpose_mem<<<dim3(PROTO / 8), dim3(256), 0, stream>>>(memory, memTw);
    top_kernel<<<dim3(NROWS / ROWS_PER_BLK), dim3(256), 0, stream>>>(
        repres, memory, memTw, top1w, d1w, negw, flagw);
    combo_kernel<<<dim3(MASK_BLOCKS + 1 + OUT_BLOCKS), dim3(256), 0, stream>>>(
        repres, memory, memTw, top1w, d1w, negw, flagw, out);
}